// Round 4
// baseline (205.746 us; speedup 1.0000x reference)
//
#include <hip/hip_runtime.h>
#include <hip/hip_fp16.h>

// GridSmoother: per-(batch,channel) CG solve of (I + graph-Laplacian) x = b
// on a 128x160 grid. One workgroup (512 threads = 8 waves) per system;
// 256 systems = 256 workgroups = 1 block/CU. CG vectors p/r in registers,
// x in LDS, wy weights in LDS; wave-edge column halos + reduction slots in
// LDS. 2 barriers/iteration.
//
// Round-5 changes vs round-4 (143 us, VGPR pinned at 128, ~2.1 MB/iter spill
// traffic: extra WRITE 34 MB over the 21 MB output):
//  * The 128-VGPR cap at NT=512 is immovable (launch_bounds AND
//    amdgpu_waves_per_eu both failed to raise it). So: fit under it.
//    Live state 190 -> ~114 via three cuts, all staying f32:
//    1. wyu0h eliminated: up-term for row i0 == -shfl_up(down-term of row
//       i1 on lane-1): wu0*(c0-up0) = -shfl_up(wy1*(c1-dn1)). Same shfl
//       count, -10 regs, lane 0 masked to 0.
//    2. wy weight pairs moved to LDS [k][tid] (packed half2, self-slot
//       read, conflict-free, no barrier needed): -20 regs.
//    3. Ap never stored: stencil #1 computes only pAp; after alpha, stencil
//       #2 recomputes a0/a1 and consumes them immediately (r/x updates
//       fused in-loop): -40 regs. ~+1 us/iter VALU vs ~4 us/iter spill
//       stalls removed (calibrated ~2 us per MB spill from rounds 0/3).
//  * LDS: xs 80K + halos 8.25K + wyls 40K = 128.3K < 160K.
//
// Thread mapping: lane l holds rows 2l,2l+1 (wave spans all 128 rows);
// wave w holds columns [20w, 20w+20). Up/down: shfl +-1 lane. Left/right:
// registers except wave edges (register halo pairs hlp/hrp, rebuilt from
// published r-edges each iteration: p_new = r + beta*p_old, beta uniform).

#define GH 128
#define GW 160
#define NW 8
#define NCOL 20
#define NT 512
#define NITER 16

__device__ __forceinline__ float wave_sum(float v) {
  #pragma unroll
  for (int off = 32; off > 0; off >>= 1) v += __shfl_xor(v, off, 64);
  return v;
}

// Stencil: a = c + wxl*(c-left) + wxr*(c-right) + up-term + down-term.
// Boundary terms vanish because the corresponding weights are zeroed.
// hy couples (i0,i1) in-thread; t couples i1 with lane+1's i0; the i0
// up-term is -shfl_up(t). ACCUM may use k, c0,c1, a0,a1.
#define STENCIL(ACCUM)                                                        \
  {                                                                           \
    float lf0 = hlp.x, lf1 = hlp.y;                                           \
    float wxl0 = __low2float(wxlh), wxl1 = __high2float(wxlh);                \
    _Pragma("unroll")                                                         \
    for (int k = 0; k < NCOL; ++k) {                                          \
      const float c0 = p0[k], c1 = p1[k];                                     \
      const float rt0 = (k == NCOL - 1) ? hrp.x : p0[(k + 1) % NCOL];         \
      const float rt1 = (k == NCOL - 1) ? hrp.y : p1[(k + 1) % NCOL];         \
      const float dn1 = __shfl_down(c0, 1, 64); /* row i1+1 = lane+1's p0 */  \
      const __half2 wyw = wyls[k][tid];                                       \
      const float wy0 = __low2float(wyw), wy1 = __high2float(wyw);            \
      const float wxr0 = __low2float(wxh[k]), wxr1 = __high2float(wxh[k]);    \
      const float hy = wy0 * (c0 - c1);   /* i0<->i1 coupling */              \
      const float t = wy1 * (c1 - dn1);   /* i1<->down coupling */            \
      float tu = __shfl_up(t, 1, 64);     /* lane-1's t = my up-term (neg) */ \
      tu = (lane == 0) ? 0.f : tu;        /* row 0 has no up neighbor */      \
      const float a0 = c0 + wxl0 * (c0 - lf0) + wxr0 * (c0 - rt0) - tu + hy;  \
      const float a1 = c1 + wxl1 * (c1 - lf1) + wxr1 * (c1 - rt1) - hy + t;   \
      ACCUM;                                                                  \
      lf0 = c0; lf1 = c1; wxl0 = wxr0; wxl1 = wxr1;                           \
    }                                                                         \
  }

#define WRITE_HALO_P()                                                        \
  {                                                                           \
    *(float2*)&haloL[wv][i0] = make_float2(p0[0], p1[0]);                     \
    *(float2*)&haloR[wv][i0] = make_float2(p0[NCOL - 1], p1[NCOL - 1]);       \
  }

#define READ_HALO_REGS()                                                      \
  {                                                                           \
    hlp = *(const float2*)&haloR[wl_][i0];                                    \
    hrp = *(const float2*)&haloL[wr_][i0];                                    \
  }

__global__ __attribute__((amdgpu_flat_work_group_size(NT, NT),
                          amdgpu_waves_per_eu(2, 2)))
void GridSmoother_cg_kernel(
    const float* __restrict__ ae, const float* __restrict__ wxwy,
    float* __restrict__ out) {
  const int tid = threadIdx.x;
  const int wv = tid >> 6;
  const int lane = tid & 63;
  const int prob = blockIdx.x;  // b*16 + d
  const int bb = prob >> 4;

  const int i0 = lane << 1;
  const int i1 = i0 | 1;
  const int j0 = wv * NCOL;
  const int wl_ = (wv + NW - 1) & (NW - 1);
  const int wr_ = (wv + 1) & (NW - 1);

  const float* __restrict__ bsrc = ae + (size_t)prob * (GH * GW);
  const float* __restrict__ wxp = wxwy + (size_t)(2 * bb) * (GH * GW);
  const float* __restrict__ wyp = wxp + (GH * GW);
  float* __restrict__ outp = out + (size_t)prob * (GH * GW);

  __shared__ float haloL[NW][GH];  // published leftmost-column edge values
  __shared__ float haloR[NW][GH];  // published rightmost-column edge values
  __shared__ __align__(16) float red[2][NW];  // cross-wave reduction slots
  __shared__ float xs0[NCOL][NT];  // x for row i0, [k][tid]: conflict-free
  __shared__ float xs1[NCOL][NT];  // x for row i1
  __shared__ __half2 wyls[NCOL][NT];  // (wy[i0], wy[i1]) down weights

  float p0[NCOL], p1[NCOL], r0[NCOL], r1[NCOL];
  float2 hlp, hrp;             // left/right neighbour p-edge (rows i0,i1)
  __half2 wxh[NCOL];           // (wx[i0][j], wx[i1][j]) right weights
  __half2 wxlh;                // left-edge weight pair (col j0-1)

  // ---- load b;  x = p = b (jax cg uses x0 = b) ----
  {
    const float4* s0 = (const float4*)(bsrc + i0 * GW + j0);
    const float4* s1 = (const float4*)(bsrc + i1 * GW + j0);
    #pragma unroll
    for (int q = 0; q < NCOL / 4; ++q) {
      float4 v0 = s0[q], v1 = s1[q];
      p0[4 * q + 0] = v0.x; p0[4 * q + 1] = v0.y;
      p0[4 * q + 2] = v0.z; p0[4 * q + 3] = v0.w;
      p1[4 * q + 0] = v1.x; p1[4 * q + 1] = v1.y;
      p1[4 * q + 2] = v1.z; p1[4 * q + 3] = v1.w;
    }
  }
  #pragma unroll
  for (int k = 0; k < NCOL; ++k) { xs0[k][tid] = p0[k]; xs1[k][tid] = p1[k]; }

  // ---- load weights (zeroed at domain boundaries), pack to fp16 ----
  {
    const float4* a0p = (const float4*)(wxp + i0 * GW + j0);
    const float4* a1p = (const float4*)(wxp + i1 * GW + j0);
    const float4* c0p = (const float4*)(wyp + i0 * GW + j0);
    const float4* c1p = (const float4*)(wyp + i1 * GW + j0);
    #pragma unroll
    for (int q = 0; q < NCOL / 4; ++q) {
      float4 a0 = a0p[q], a1 = a1p[q], c0 = c0p[q], c1 = c1p[q];
      const float e0[4] = {a0.x, a0.y, a0.z, a0.w};
      const float e1[4] = {a1.x, a1.y, a1.z, a1.w};
      const float f0[4] = {c0.x, c0.y, c0.z, c0.w};
      const float f1[4] = {c1.x, c1.y, c1.z, c1.w};
      #pragma unroll
      for (int e = 0; e < 4; ++e) {
        const int k = 4 * q + e;
        const bool lastcol = (j0 + k == GW - 1);  // wx_e excludes col W-1
        wxh[k] = __floats2half2_rn(lastcol ? 0.f : e0[e],
                                   lastcol ? 0.f : e1[e]);
        const float wyd0 = f0[e];                        // i0 <= 126 always
        const float wyd1 = (i1 == GH - 1) ? 0.f : f1[e]; // wy_e excludes row H-1
        wyls[k][tid] = __floats2half2_rn(wyd0, wyd1);    // self-slot: no sync
      }
    }
    float wl0 = 0.f, wl1 = 0.f;
    if (wv > 0) {
      wl0 = wxp[i0 * GW + (j0 - 1)];
      wl1 = wxp[i1 * GW + (j0 - 1)];
    }
    wxlh = __floats2half2_rn(wl0, wl1);
  }

  // ---- r = b - A*b ; p = r ; rr_old = <r,r> ----
  WRITE_HALO_P();            // b edges
  __syncthreads();
  READ_HALO_REGS();          // b edges -> registers
  float rr = 0.f;
  STENCIL(
    r0[k] = c0 - a0;         // x == p == b here
    r1[k] = c1 - a1;
    rr += r0[k] * r0[k] + r1[k] * r1[k];
  )
  #pragma unroll
  for (int k = 0; k < NCOL; ++k) { p0[k] = r0[k]; p1[k] = r1[k]; }
  rr = wave_sum(rr);
  __syncthreads();           // all waves done reading b-edge halos
  WRITE_HALO_P();            // r edges (p == r)
  if (lane == 0) red[1][wv] = rr;
  __syncthreads();
  float rr_old = 0.f;
  {
    const float4* rp = (const float4*)&red[1][0];
    #pragma unroll
    for (int q = 0; q < NW / 4; ++q) {
      float4 v = rp[q];
      rr_old += (v.x + v.y) + (v.z + v.w);
    }
  }
  READ_HALO_REGS();          // r edges == initial p edges -> registers

  // ---- CG main loop: 2 barriers / iteration, Ap never stored ----
  #pragma unroll 1
  for (int it = 0; it < NITER; ++it) {
    // stencil #1: pAp only
    float pAp = 0.f;
    STENCIL(pAp += c0 * a0 + c1 * a1;)
    pAp = wave_sum(pAp);
    if (lane == 0) red[0][wv] = pAp;
    __syncthreads();  // barrier A
    float s = 0.f;
    {
      const float4* rp = (const float4*)&red[0][0];
      #pragma unroll
      for (int q = 0; q < NW / 4; ++q) {
        float4 v = rp[q];
        s += (v.x + v.y) + (v.z + v.w);
      }
    }
    const float alpha = rr_old / fmaxf(s, 1e-37f);

    // stencil #2: recompute a and consume immediately (x += a*p, r -= a*Ap)
    float rrn_loc = 0.f;
    STENCIL(
      xs0[k][tid] = fmaf(alpha, c0, xs0[k][tid]);
      xs1[k][tid] = fmaf(alpha, c1, xs1[k][tid]);
      r0[k] = fmaf(-alpha, a0, r0[k]);
      r1[k] = fmaf(-alpha, a1, r1[k]);
      rrn_loc += r0[k] * r0[k] + r1[k] * r1[k];
    )
    if (it == NITER - 1) break;  // x is final; tail below is dead

    // publish r edges (consumed after barrier B to rebuild p-edge registers)
    *(float2*)&haloL[wv][i0] = make_float2(r0[0], r1[0]);
    *(float2*)&haloR[wv][i0] = make_float2(r0[NCOL - 1], r1[NCOL - 1]);
    rrn_loc = wave_sum(rrn_loc);
    if (lane == 0) red[1][wv] = rrn_loc;
    __syncthreads();  // barrier B
    float rrn = 0.f;
    {
      const float4* rp = (const float4*)&red[1][0];
      #pragma unroll
      for (int q = 0; q < NW / 4; ++q) {
        float4 v = rp[q];
        rrn += (v.x + v.y) + (v.z + v.w);
      }
    }
    const float beta = rrn / fmaxf(rr_old, 1e-37f);
    rr_old = rrn;

    #pragma unroll
    for (int k = 0; k < NCOL; ++k) {
      p0[k] = fmaf(beta, p0[k], r0[k]);
      p1[k] = fmaf(beta, p1[k], r1[k]);
    }
    // rebuild neighbour p-edges locally: p_edge_new = r_edge + beta*p_edge_old
    {
      const float2 hlr = *(const float2*)&haloR[wl_][i0];
      const float2 hrr = *(const float2*)&haloL[wr_][i0];
      hlp.x = fmaf(beta, hlp.x, hlr.x);
      hlp.y = fmaf(beta, hlp.y, hlr.y);
      hrp.x = fmaf(beta, hrp.x, hrr.x);
      hrp.y = fmaf(beta, hrp.y, hrr.y);
    }
  }

  // ---- store x (each thread reads only its own LDS slots; no barrier
  //      needed: xs[k][tid] was last written by this thread) ----
  {
    float4* o0 = (float4*)(outp + i0 * GW + j0);
    float4* o1 = (float4*)(outp + i1 * GW + j0);
    #pragma unroll
    for (int q = 0; q < NCOL / 4; ++q) {
      o0[q] = make_float4(xs0[4 * q + 0][tid], xs0[4 * q + 1][tid],
                          xs0[4 * q + 2][tid], xs0[4 * q + 3][tid]);
      o1[q] = make_float4(xs1[4 * q + 0][tid], xs1[4 * q + 1][tid],
                          xs1[4 * q + 2][tid], xs1[4 * q + 3][tid]);
    }
  }
}

extern "C" void kernel_launch(void* const* d_in, const int* in_sizes, int n_in,
                              void* d_out, int out_size, void* d_ws,
                              size_t ws_size, hipStream_t stream) {
  const float* ae = (const float*)d_in[0];      // (16,16,128,160) f32
  const float* wxwy = (const float*)d_in[1];    // (16,2,128,160) f32
  float* out = (float*)d_out;                   // (16,16,128,160) f32
  const int nprob = in_sizes[0] / (GH * GW);    // 256 systems
  GridSmoother_cg_kernel<<<dim3(nprob), dim3(NT), 0, stream>>>(ae, wxwy, out);
}

// Round 5
// 169.574 us; speedup vs baseline: 1.2133x; 1.2133x over previous
//
#include <hip/hip_runtime.h>
#include <hip/hip_fp16.h>

// GridSmoother: per-(batch,channel) CG solve of (I + graph-Laplacian) x = b
// on a 128x160 grid. One workgroup (512 threads = 8 waves) per system;
// 256 systems = 256 workgroups = 1 block/CU. CG vectors p/r/Ap in registers,
// x in LDS (conflict-free [k][tid] layout); wave-edge column halos +
// reduction slots in LDS. 2 barriers/iteration.
//
// Round-6 changes vs round-5 (150 us; Ap-recompute cost > spill savings,
// WRITE still 51.6 MB) and round-4 (best: 137-143 us dispatch):
//  * Revert to the round-4 structure (Ap stored, single stencil/iter) --
//    best measured.
//  * amdgpu_num_vgpr(256): third, mechanistically different cap attempt.
//    Evidence: all configs satisfy cap*waves_per_block = 1024 (i.e. the
//    toolchain sizes registers for TWO workgroups/CU and spills to meet it);
//    launch_bounds and amdgpu_waves_per_eu both failed to override. num_vgpr
//    is a direct allocator budget, not an occupancy hint. Live state ~152
//    fits 256 with zero spill. Failure signature: VGPR_Count=128 again.
//  * Keep round-5's validated wyu0h elimination (up-term for row i0 ==
//    -shfl_up(wy1*(c1-dn1)) from lane-1; lane 0 masked): -10 regs, same
//    shfl count, absmax unchanged when tested in round 5.
//
// Thread mapping: lane l holds rows 2l,2l+1 (wave spans all 128 rows);
// wave w holds columns [20w, 20w+20). Up/down: shfl +-1 lane. Left/right:
// registers except wave edges (register halo pairs hlp/hrp, rebuilt from
// published r-edges each iteration: p_new = r + beta*p_old, beta uniform).
// Weights packed fp16 (pairs per column).

#define GH 128
#define GW 160
#define NW 8
#define NCOL 20
#define NT 512
#define NITER 16

__device__ __forceinline__ float wave_sum(float v) {
  #pragma unroll
  for (int off = 32; off > 0; off >>= 1) v += __shfl_xor(v, off, 64);
  return v;
}

// Stencil: a = c + wxl*(c-left) + wxr*(c-right) + up-term + down-term.
// Boundary terms vanish because the corresponding weights are zeroed.
// hy couples (i0,i1) in-thread; t couples i1 with lane+1's i0; the i0
// up-term is -shfl_up(t). ACCUM may use k, c0,c1, a0,a1.
#define STENCIL(ACCUM)                                                        \
  {                                                                           \
    float lf0 = hlp.x, lf1 = hlp.y;                                           \
    float wxl0 = __low2float(wxlh), wxl1 = __high2float(wxlh);                \
    _Pragma("unroll")                                                         \
    for (int k = 0; k < NCOL; ++k) {                                          \
      const float c0 = p0[k], c1 = p1[k];                                     \
      const float rt0 = (k == NCOL - 1) ? hrp.x : p0[(k + 1) % NCOL];         \
      const float rt1 = (k == NCOL - 1) ? hrp.y : p1[(k + 1) % NCOL];         \
      const float dn1 = __shfl_down(c0, 1, 64); /* row i1+1 = lane+1's p0 */  \
      const float wy0 = __low2float(wyh[k]), wy1 = __high2float(wyh[k]);      \
      const float wxr0 = __low2float(wxh[k]), wxr1 = __high2float(wxh[k]);    \
      const float hy = wy0 * (c0 - c1);   /* i0<->i1 coupling */              \
      const float t = wy1 * (c1 - dn1);   /* i1<->down coupling */            \
      float tu = __shfl_up(t, 1, 64);     /* lane-1's t = my up-term (neg) */ \
      tu = (lane == 0) ? 0.f : tu;        /* row 0 has no up neighbor */      \
      const float a0 = c0 + wxl0 * (c0 - lf0) + wxr0 * (c0 - rt0) - tu + hy;  \
      const float a1 = c1 + wxl1 * (c1 - lf1) + wxr1 * (c1 - rt1) - hy + t;   \
      Ap0[k] = a0; Ap1[k] = a1;                                               \
      ACCUM;                                                                  \
      lf0 = c0; lf1 = c1; wxl0 = wxr0; wxl1 = wxr1;                           \
    }                                                                         \
  }

#define WRITE_HALO_P()                                                        \
  {                                                                           \
    *(float2*)&haloL[wv][i0] = make_float2(p0[0], p1[0]);                     \
    *(float2*)&haloR[wv][i0] = make_float2(p0[NCOL - 1], p1[NCOL - 1]);       \
  }

#define READ_HALO_REGS()                                                      \
  {                                                                           \
    hlp = *(const float2*)&haloR[wl_][i0];                                    \
    hrp = *(const float2*)&haloL[wr_][i0];                                    \
  }

__global__ __attribute__((amdgpu_flat_work_group_size(NT, NT),
                          amdgpu_num_vgpr(256)))
void GridSmoother_cg_kernel(
    const float* __restrict__ ae, const float* __restrict__ wxwy,
    float* __restrict__ out) {
  const int tid = threadIdx.x;
  const int wv = tid >> 6;
  const int lane = tid & 63;
  const int prob = blockIdx.x;  // b*16 + d
  const int bb = prob >> 4;

  const int i0 = lane << 1;
  const int i1 = i0 | 1;
  const int j0 = wv * NCOL;
  const int wl_ = (wv + NW - 1) & (NW - 1);
  const int wr_ = (wv + 1) & (NW - 1);

  const float* __restrict__ bsrc = ae + (size_t)prob * (GH * GW);
  const float* __restrict__ wxp = wxwy + (size_t)(2 * bb) * (GH * GW);
  const float* __restrict__ wyp = wxp + (GH * GW);
  float* __restrict__ outp = out + (size_t)prob * (GH * GW);

  __shared__ float haloL[NW][GH];  // published leftmost-column edge values
  __shared__ float haloR[NW][GH];  // published rightmost-column edge values
  __shared__ __align__(16) float red[2][NW];  // cross-wave reduction slots
  __shared__ float xs0[NCOL][NT];  // x for row i0, [k][tid]: conflict-free
  __shared__ float xs1[NCOL][NT];  // x for row i1

  float p0[NCOL], p1[NCOL], r0[NCOL], r1[NCOL];
  float Ap0[NCOL], Ap1[NCOL];
  float2 hlp, hrp;             // left/right neighbour p-edge (rows i0,i1)
  __half2 wxh[NCOL];           // (wx[i0][j], wx[i1][j]) right weights
  __half2 wyh[NCOL];           // (wy[i0][j], wy[i1][j]) down weights
  __half2 wxlh;                // left-edge weight pair (col j0-1)

  // ---- load b;  x = p = b (jax cg uses x0 = b) ----
  {
    const float4* s0 = (const float4*)(bsrc + i0 * GW + j0);
    const float4* s1 = (const float4*)(bsrc + i1 * GW + j0);
    #pragma unroll
    for (int q = 0; q < NCOL / 4; ++q) {
      float4 v0 = s0[q], v1 = s1[q];
      p0[4 * q + 0] = v0.x; p0[4 * q + 1] = v0.y;
      p0[4 * q + 2] = v0.z; p0[4 * q + 3] = v0.w;
      p1[4 * q + 0] = v1.x; p1[4 * q + 1] = v1.y;
      p1[4 * q + 2] = v1.z; p1[4 * q + 3] = v1.w;
    }
  }
  #pragma unroll
  for (int k = 0; k < NCOL; ++k) { xs0[k][tid] = p0[k]; xs1[k][tid] = p1[k]; }

  // ---- load weights (zeroed at domain boundaries), pack to fp16 ----
  {
    const float4* a0p = (const float4*)(wxp + i0 * GW + j0);
    const float4* a1p = (const float4*)(wxp + i1 * GW + j0);
    const float4* c0p = (const float4*)(wyp + i0 * GW + j0);
    const float4* c1p = (const float4*)(wyp + i1 * GW + j0);
    #pragma unroll
    for (int q = 0; q < NCOL / 4; ++q) {
      float4 a0 = a0p[q], a1 = a1p[q], c0 = c0p[q], c1 = c1p[q];
      const float e0[4] = {a0.x, a0.y, a0.z, a0.w};
      const float e1[4] = {a1.x, a1.y, a1.z, a1.w};
      const float f0[4] = {c0.x, c0.y, c0.z, c0.w};
      const float f1[4] = {c1.x, c1.y, c1.z, c1.w};
      #pragma unroll
      for (int e = 0; e < 4; ++e) {
        const int k = 4 * q + e;
        const bool lastcol = (j0 + k == GW - 1);  // wx_e excludes col W-1
        wxh[k] = __floats2half2_rn(lastcol ? 0.f : e0[e],
                                   lastcol ? 0.f : e1[e]);
        const float wyd0 = f0[e];                        // i0 <= 126 always
        const float wyd1 = (i1 == GH - 1) ? 0.f : f1[e]; // wy_e excludes row H-1
        wyh[k] = __floats2half2_rn(wyd0, wyd1);
      }
    }
    float wl0 = 0.f, wl1 = 0.f;
    if (wv > 0) {
      wl0 = wxp[i0 * GW + (j0 - 1)];
      wl1 = wxp[i1 * GW + (j0 - 1)];
    }
    wxlh = __floats2half2_rn(wl0, wl1);
  }

  // ---- r = b - A*b ; p = r ; rr_old = <r,r> ----
  WRITE_HALO_P();            // b edges
  __syncthreads();
  READ_HALO_REGS();          // b edges -> registers
  STENCIL(;)
  float rr = 0.f;
  #pragma unroll
  for (int k = 0; k < NCOL; ++k) {
    r0[k] = p0[k] - Ap0[k];   // x == p == b here
    r1[k] = p1[k] - Ap1[k];
    rr += r0[k] * r0[k] + r1[k] * r1[k];
    p0[k] = r0[k]; p1[k] = r1[k];
  }
  rr = wave_sum(rr);
  __syncthreads();           // all waves done reading b-edge halos
  WRITE_HALO_P();            // r edges (p == r)
  if (lane == 0) red[1][wv] = rr;
  __syncthreads();
  float rr_old = 0.f;
  {
    const float4* rp = (const float4*)&red[1][0];
    #pragma unroll
    for (int q = 0; q < NW / 4; ++q) {
      float4 v = rp[q];
      rr_old += (v.x + v.y) + (v.z + v.w);
    }
  }
  READ_HALO_REGS();          // r edges == initial p edges -> registers

  // ---- CG main loop: 2 barriers / iteration ----
  #pragma unroll 1
  for (int it = 0; it < NITER; ++it) {
    float pAp = 0.f;
    STENCIL(pAp += c0 * a0 + c1 * a1;)
    pAp = wave_sum(pAp);
    if (lane == 0) red[0][wv] = pAp;
    __syncthreads();  // barrier A
    float s = 0.f;
    {
      const float4* rp = (const float4*)&red[0][0];
      #pragma unroll
      for (int q = 0; q < NW / 4; ++q) {
        float4 v = rp[q];
        s += (v.x + v.y) + (v.z + v.w);
      }
    }
    const float alpha = rr_old / fmaxf(s, 1e-37f);

    float rrn_loc = 0.f;
    #pragma unroll
    for (int k = 0; k < NCOL; ++k) {
      xs0[k][tid] = fmaf(alpha, p0[k], xs0[k][tid]);
      xs1[k][tid] = fmaf(alpha, p1[k], xs1[k][tid]);
      r0[k] = fmaf(-alpha, Ap0[k], r0[k]);
      r1[k] = fmaf(-alpha, Ap1[k], r1[k]);
      rrn_loc += r0[k] * r0[k] + r1[k] * r1[k];
    }
    if (it == NITER - 1) break;  // x is final; tail below is dead

    // publish r edges (consumed after barrier B to rebuild p-edge registers)
    *(float2*)&haloL[wv][i0] = make_float2(r0[0], r1[0]);
    *(float2*)&haloR[wv][i0] = make_float2(r0[NCOL - 1], r1[NCOL - 1]);
    rrn_loc = wave_sum(rrn_loc);
    if (lane == 0) red[1][wv] = rrn_loc;
    __syncthreads();  // barrier B
    float rrn = 0.f;
    {
      const float4* rp = (const float4*)&red[1][0];
      #pragma unroll
      for (int q = 0; q < NW / 4; ++q) {
        float4 v = rp[q];
        rrn += (v.x + v.y) + (v.z + v.w);
      }
    }
    const float beta = rrn / fmaxf(rr_old, 1e-37f);
    rr_old = rrn;

    #pragma unroll
    for (int k = 0; k < NCOL; ++k) {
      p0[k] = fmaf(beta, p0[k], r0[k]);
      p1[k] = fmaf(beta, p1[k], r1[k]);
    }
    // rebuild neighbour p-edges locally: p_edge_new = r_edge + beta*p_edge_old
    {
      const float2 hlr = *(const float2*)&haloR[wl_][i0];
      const float2 hrr = *(const float2*)&haloL[wr_][i0];
      hlp.x = fmaf(beta, hlp.x, hlr.x);
      hlp.y = fmaf(beta, hlp.y, hlr.y);
      hrp.x = fmaf(beta, hrp.x, hrr.x);
      hrp.y = fmaf(beta, hrp.y, hrr.y);
    }
  }

  // ---- store x (each thread reads only its own LDS slots; no barrier
  //      needed: xs[k][tid] was last written by this thread) ----
  {
    float4* o0 = (float4*)(outp + i0 * GW + j0);
    float4* o1 = (float4*)(outp + i1 * GW + j0);
    #pragma unroll
    for (int q = 0; q < NCOL / 4; ++q) {
      o0[q] = make_float4(xs0[4 * q + 0][tid], xs0[4 * q + 1][tid],
                          xs0[4 * q + 2][tid], xs0[4 * q + 3][tid]);
      o1[q] = make_float4(xs1[4 * q + 0][tid], xs1[4 * q + 1][tid],
                          xs1[4 * q + 2][tid], xs1[4 * q + 3][tid]);
    }
  }
}

extern "C" void kernel_launch(void* const* d_in, const int* in_sizes, int n_in,
                              void* d_out, int out_size, void* d_ws,
                              size_t ws_size, hipStream_t stream) {
  const float* ae = (const float*)d_in[0];      // (16,16,128,160) f32
  const float* wxwy = (const float*)d_in[1];    // (16,2,128,160) f32
  float* out = (float*)d_out;                   // (16,16,128,160) f32
  const int nprob = in_sizes[0] / (GH * GW);    // 256 systems
  GridSmoother_cg_kernel<<<dim3(nprob), dim3(NT), 0, stream>>>(ae, wxwy, out);
}

// Round 6
// 142.718 us; speedup vs baseline: 1.4416x; 1.1882x over previous
//
#include <hip/hip_runtime.h>
#include <hip/hip_fp16.h>

// GridSmoother: per-(batch,channel) CG solve of (I + graph-Laplacian) x = b
// on a 128x160 grid. One workgroup (512 threads = 8 waves) per system;
// 256 systems = 256 workgroups = 1 block/CU. CG vectors p/r in f32 registers,
// Ap in PACKED fp16 registers, x in LDS, wy weights in LDS; wave-edge column
// halos + reduction slots in LDS. 2 barriers/iteration.
//
// Round-7 changes vs round-6 (117 us dispatch; VGPR cap pinned at 128 for the
// 5th straight config -> empirical law: cap = 1024/waves_per_block, allocator
// always budgets 2 workgroups/CU; WRITE 45.5 MB = ~24 MB spill @ ~2us/MB):
//  * STOP fighting the cap -- fit under 128. Live state ~153 -> ~117:
//    1. wy weight pairs -> LDS [k][tid] half2 (self-slot read, consecutive
//       lanes = 2-way bank aliasing = free): -10 regs. LDS 128.2 KB.
//    2. Ap stored as __half2 Aph[NCOL]: -20 regs. pAp dot uses exact f32
//       a0/a1 inside the stencil (before rounding); initial residual uses
//       f32 directly; only the r -= alpha*Ap consumer sees fp16 Ap
//       (rel ~5e-4 -> inexact-CG floor ~1e-3*||b||, x-err ~5e-3, far below
//       the 1.56e-2 fp16-weight floor; threshold 7.8e-2).
//  * Keeps: Ap-stored single stencil/iter (round-4 structure, best), 2
//    barriers/iter with register halos rebuilt from published r-edges,
//    wyu0h elimination (up-term = -shfl_up(down-term)), dead-tail skip.
//
// Thread mapping: lane l holds rows 2l,2l+1 (wave spans all 128 rows);
// wave w holds columns [20w, 20w+20). Up/down: shfl +-1 lane. Left/right:
// registers except wave edges (register halo pairs hlp/hrp; p_new =
// r + beta*p_old with block-uniform beta).

#define GH 128
#define GW 160
#define NW 8
#define NCOL 20
#define NT 512
#define NITER 16

__device__ __forceinline__ float wave_sum(float v) {
  #pragma unroll
  for (int off = 32; off > 0; off >>= 1) v += __shfl_xor(v, off, 64);
  return v;
}

// Stencil: a = c + wxl*(c-left) + wxr*(c-right) + up-term + down-term.
// Boundary terms vanish because the corresponding weights are zeroed.
// hy couples (i0,i1) in-thread; t couples i1 with lane+1's i0; the i0
// up-term is -shfl_up(t). ACCUM may use k, c0,c1, a0,a1.
#define STENCIL(ACCUM)                                                        \
  {                                                                           \
    float lf0 = hlp.x, lf1 = hlp.y;                                           \
    float wxl0 = __low2float(wxlh), wxl1 = __high2float(wxlh);                \
    _Pragma("unroll")                                                         \
    for (int k = 0; k < NCOL; ++k) {                                          \
      const float c0 = p0[k], c1 = p1[k];                                     \
      const float rt0 = (k == NCOL - 1) ? hrp.x : p0[(k + 1) % NCOL];         \
      const float rt1 = (k == NCOL - 1) ? hrp.y : p1[(k + 1) % NCOL];         \
      const float dn1 = __shfl_down(c0, 1, 64); /* row i1+1 = lane+1's p0 */  \
      const __half2 wyw = wyls[k][tid];                                       \
      const float wy0 = __low2float(wyw), wy1 = __high2float(wyw);            \
      const float wxr0 = __low2float(wxh[k]), wxr1 = __high2float(wxh[k]);    \
      const float hy = wy0 * (c0 - c1);   /* i0<->i1 coupling */              \
      const float t = wy1 * (c1 - dn1);   /* i1<->down coupling */            \
      float tu = __shfl_up(t, 1, 64);     /* lane-1's t = my up-term (neg) */ \
      tu = (lane == 0) ? 0.f : tu;        /* row 0 has no up neighbor */      \
      const float a0 = c0 + wxl0 * (c0 - lf0) + wxr0 * (c0 - rt0) - tu + hy;  \
      const float a1 = c1 + wxl1 * (c1 - lf1) + wxr1 * (c1 - rt1) - hy + t;   \
      ACCUM;                                                                  \
      lf0 = c0; lf1 = c1; wxl0 = wxr0; wxl1 = wxr1;                           \
    }                                                                         \
  }

#define WRITE_HALO_P()                                                        \
  {                                                                           \
    *(float2*)&haloL[wv][i0] = make_float2(p0[0], p1[0]);                     \
    *(float2*)&haloR[wv][i0] = make_float2(p0[NCOL - 1], p1[NCOL - 1]);       \
  }

#define READ_HALO_REGS()                                                      \
  {                                                                           \
    hlp = *(const float2*)&haloR[wl_][i0];                                    \
    hrp = *(const float2*)&haloL[wr_][i0];                                    \
  }

__global__ __attribute__((amdgpu_flat_work_group_size(NT, NT)))
void GridSmoother_cg_kernel(
    const float* __restrict__ ae, const float* __restrict__ wxwy,
    float* __restrict__ out) {
  const int tid = threadIdx.x;
  const int wv = tid >> 6;
  const int lane = tid & 63;
  const int prob = blockIdx.x;  // b*16 + d
  const int bb = prob >> 4;

  const int i0 = lane << 1;
  const int i1 = i0 | 1;
  const int j0 = wv * NCOL;
  const int wl_ = (wv + NW - 1) & (NW - 1);
  const int wr_ = (wv + 1) & (NW - 1);

  const float* __restrict__ bsrc = ae + (size_t)prob * (GH * GW);
  const float* __restrict__ wxp = wxwy + (size_t)(2 * bb) * (GH * GW);
  const float* __restrict__ wyp = wxp + (GH * GW);
  float* __restrict__ outp = out + (size_t)prob * (GH * GW);

  __shared__ float haloL[NW][GH];  // published leftmost-column edge values
  __shared__ float haloR[NW][GH];  // published rightmost-column edge values
  __shared__ __align__(16) float red[2][NW];  // cross-wave reduction slots
  __shared__ float xs0[NCOL][NT];  // x for row i0, [k][tid]: conflict-free
  __shared__ float xs1[NCOL][NT];  // x for row i1
  __shared__ __half2 wyls[NCOL][NT];  // (wy[i0], wy[i1]) down-weight pairs

  float p0[NCOL], p1[NCOL], r0[NCOL], r1[NCOL];
  __half2 Aph[NCOL];           // packed (Ap[i0], Ap[i1]) -- fp16 storage
  float2 hlp, hrp;             // left/right neighbour p-edge (rows i0,i1)
  __half2 wxh[NCOL];           // (wx[i0][j], wx[i1][j]) right weights
  __half2 wxlh;                // left-edge weight pair (col j0-1)

  // ---- load b;  x = p = b (jax cg uses x0 = b) ----
  {
    const float4* s0 = (const float4*)(bsrc + i0 * GW + j0);
    const float4* s1 = (const float4*)(bsrc + i1 * GW + j0);
    #pragma unroll
    for (int q = 0; q < NCOL / 4; ++q) {
      float4 v0 = s0[q], v1 = s1[q];
      p0[4 * q + 0] = v0.x; p0[4 * q + 1] = v0.y;
      p0[4 * q + 2] = v0.z; p0[4 * q + 3] = v0.w;
      p1[4 * q + 0] = v1.x; p1[4 * q + 1] = v1.y;
      p1[4 * q + 2] = v1.z; p1[4 * q + 3] = v1.w;
    }
  }
  #pragma unroll
  for (int k = 0; k < NCOL; ++k) { xs0[k][tid] = p0[k]; xs1[k][tid] = p1[k]; }

  // ---- load weights (zeroed at domain boundaries), pack to fp16 ----
  {
    const float4* a0p = (const float4*)(wxp + i0 * GW + j0);
    const float4* a1p = (const float4*)(wxp + i1 * GW + j0);
    const float4* c0p = (const float4*)(wyp + i0 * GW + j0);
    const float4* c1p = (const float4*)(wyp + i1 * GW + j0);
    #pragma unroll
    for (int q = 0; q < NCOL / 4; ++q) {
      float4 a0 = a0p[q], a1 = a1p[q], c0 = c0p[q], c1 = c1p[q];
      const float e0[4] = {a0.x, a0.y, a0.z, a0.w};
      const float e1[4] = {a1.x, a1.y, a1.z, a1.w};
      const float f0[4] = {c0.x, c0.y, c0.z, c0.w};
      const float f1[4] = {c1.x, c1.y, c1.z, c1.w};
      #pragma unroll
      for (int e = 0; e < 4; ++e) {
        const int k = 4 * q + e;
        const bool lastcol = (j0 + k == GW - 1);  // wx_e excludes col W-1
        wxh[k] = __floats2half2_rn(lastcol ? 0.f : e0[e],
                                   lastcol ? 0.f : e1[e]);
        const float wyd0 = f0[e];                        // i0 <= 126 always
        const float wyd1 = (i1 == GH - 1) ? 0.f : f1[e]; // wy_e excludes row H-1
        wyls[k][tid] = __floats2half2_rn(wyd0, wyd1);    // self-slot: no sync
      }
    }
    float wl0 = 0.f, wl1 = 0.f;
    if (wv > 0) {
      wl0 = wxp[i0 * GW + (j0 - 1)];
      wl1 = wxp[i1 * GW + (j0 - 1)];
    }
    wxlh = __floats2half2_rn(wl0, wl1);
  }

  // ---- r = b - A*b ; p = r ; rr_old = <r,r> (all f32; Aph not used) ----
  WRITE_HALO_P();            // b edges
  __syncthreads();
  READ_HALO_REGS();          // b edges -> registers
  float rr = 0.f;
  STENCIL(
    r0[k] = c0 - a0;         // x == p == b here
    r1[k] = c1 - a1;
    rr += r0[k] * r0[k] + r1[k] * r1[k];
  )
  #pragma unroll
  for (int k = 0; k < NCOL; ++k) { p0[k] = r0[k]; p1[k] = r1[k]; }
  rr = wave_sum(rr);
  __syncthreads();           // all waves done reading b-edge halos
  WRITE_HALO_P();            // r edges (p == r)
  if (lane == 0) red[1][wv] = rr;
  __syncthreads();
  float rr_old = 0.f;
  {
    const float4* rp = (const float4*)&red[1][0];
    #pragma unroll
    for (int q = 0; q < NW / 4; ++q) {
      float4 v = rp[q];
      rr_old += (v.x + v.y) + (v.z + v.w);
    }
  }
  READ_HALO_REGS();          // r edges == initial p edges -> registers

  // ---- CG main loop: 2 barriers / iteration ----
  #pragma unroll 1
  for (int it = 0; it < NITER; ++it) {
    float pAp = 0.f;
    STENCIL(
      pAp += c0 * a0 + c1 * a1;            // exact f32 dot
      Aph[k] = __floats2half2_rn(a0, a1);  // fp16 copy for the r-update
    )
    pAp = wave_sum(pAp);
    if (lane == 0) red[0][wv] = pAp;
    __syncthreads();  // barrier A
    float s = 0.f;
    {
      const float4* rp = (const float4*)&red[0][0];
      #pragma unroll
      for (int q = 0; q < NW / 4; ++q) {
        float4 v = rp[q];
        s += (v.x + v.y) + (v.z + v.w);
      }
    }
    const float alpha = rr_old / fmaxf(s, 1e-37f);

    float rrn_loc = 0.f;
    #pragma unroll
    for (int k = 0; k < NCOL; ++k) {
      const float ap0 = __low2float(Aph[k]);
      const float ap1 = __high2float(Aph[k]);
      xs0[k][tid] = fmaf(alpha, p0[k], xs0[k][tid]);
      xs1[k][tid] = fmaf(alpha, p1[k], xs1[k][tid]);
      r0[k] = fmaf(-alpha, ap0, r0[k]);
      r1[k] = fmaf(-alpha, ap1, r1[k]);
      rrn_loc += r0[k] * r0[k] + r1[k] * r1[k];
    }
    if (it == NITER - 1) break;  // x is final; tail below is dead

    // publish r edges (consumed after barrier B to rebuild p-edge registers)
    *(float2*)&haloL[wv][i0] = make_float2(r0[0], r1[0]);
    *(float2*)&haloR[wv][i0] = make_float2(r0[NCOL - 1], r1[NCOL - 1]);
    rrn_loc = wave_sum(rrn_loc);
    if (lane == 0) red[1][wv] = rrn_loc;
    __syncthreads();  // barrier B
    float rrn = 0.f;
    {
      const float4* rp = (const float4*)&red[1][0];
      #pragma unroll
      for (int q = 0; q < NW / 4; ++q) {
        float4 v = rp[q];
        rrn += (v.x + v.y) + (v.z + v.w);
      }
    }
    const float beta = rrn / fmaxf(rr_old, 1e-37f);
    rr_old = rrn;

    #pragma unroll
    for (int k = 0; k < NCOL; ++k) {
      p0[k] = fmaf(beta, p0[k], r0[k]);
      p1[k] = fmaf(beta, p1[k], r1[k]);
    }
    // rebuild neighbour p-edges locally: p_edge_new = r_edge + beta*p_edge_old
    {
      const float2 hlr = *(const float2*)&haloR[wl_][i0];
      const float2 hrr = *(const float2*)&haloL[wr_][i0];
      hlp.x = fmaf(beta, hlp.x, hlr.x);
      hlp.y = fmaf(beta, hlp.y, hlr.y);
      hrp.x = fmaf(beta, hrp.x, hrr.x);
      hrp.y = fmaf(beta, hrp.y, hrr.y);
    }
  }

  // ---- store x (each thread reads only its own LDS slots; no barrier
  //      needed: xs[k][tid] was last written by this thread) ----
  {
    float4* o0 = (float4*)(outp + i0 * GW + j0);
    float4* o1 = (float4*)(outp + i1 * GW + j0);
    #pragma unroll
    for (int q = 0; q < NCOL / 4; ++q) {
      o0[q] = make_float4(xs0[4 * q + 0][tid], xs0[4 * q + 1][tid],
                          xs0[4 * q + 2][tid], xs0[4 * q + 3][tid]);
      o1[q] = make_float4(xs1[4 * q + 0][tid], xs1[4 * q + 1][tid],
                          xs1[4 * q + 2][tid], xs1[4 * q + 3][tid]);
    }
  }
}

extern "C" void kernel_launch(void* const* d_in, const int* in_sizes, int n_in,
                              void* d_out, int out_size, void* d_ws,
                              size_t ws_size, hipStream_t stream) {
  const float* ae = (const float*)d_in[0];      // (16,16,128,160) f32
  const float* wxwy = (const float*)d_in[1];    // (16,2,128,160) f32
  float* out = (float*)d_out;                   // (16,16,128,160) f32
  const int nprob = in_sizes[0] / (GH * GW);    // 256 systems
  GridSmoother_cg_kernel<<<dim3(nprob), dim3(NT), 0, stream>>>(ae, wxwy, out);
}